// Round 5
// baseline (353.475 us; speedup 1.0000x reference)
//
#include <hip/hip_runtime.h>
#include <hip/hip_bf16.h>
#include <stdint.h>

typedef float f32x4 __attribute__((ext_vector_type(4)));
typedef __bf16 bf16x8 __attribute__((ext_vector_type(8)));
typedef unsigned short ushort8 __attribute__((ext_vector_type(8)));

#define NB 8
#define NS 8192
#define ND 512
#define NM (NB * NS)      // 65536 rows
#define NK 512            // reduction dim

// ---------------- f32 -> bf16 (RNE) ----------------
__device__ __forceinline__ unsigned short f2bf(float f) {
  unsigned u = __float_as_uint(f);
  u += 0x7FFFu + ((u >> 16) & 1u);
  return (unsigned short)(u >> 16);
}

__global__ __launch_bounds__(256) void cvt_bf16(const float* __restrict__ src,
                                                unsigned short* __restrict__ dst,
                                                int n8) {
  int i = blockIdx.x * 256 + threadIdx.x;
  if (i >= n8) return;
  const float4* s = reinterpret_cast<const float4*>(src + (size_t)i * 8);
  float4 v0 = s[0], v1 = s[1];
  ushort8 o;
  o[0] = f2bf(v0.x); o[1] = f2bf(v0.y); o[2] = f2bf(v0.z); o[3] = f2bf(v0.w);
  o[4] = f2bf(v1.x); o[5] = f2bf(v1.y); o[6] = f2bf(v1.z); o[7] = f2bf(v1.w);
  *reinterpret_cast<ushort8*>(dst + (size_t)i * 8) = o;
}

// ---------------- 256x256 8-phase bf16 GEMM + a/b epilogue ----------------
// Block: 256 rows x (128 hidden cols + matching 128 gate cols). 8 waves (2Mx4N),
// BK=64, 2 K-tiles/iteration, 8 phases/iteration. LDS 128KB:
//   A[2 banks][256][64] bf16 @ byte 0, B[2 banks][256][64] @ byte 65536.
// T2 XOR-swizzle (pre-swizzled global source + swizzled ds_read), T1 XCD swizzle,
// T3+T4 counted-wait phases, T5 setprio around MFMA clusters.
__global__ __launch_bounds__(512, 2) void gemm_ab(const unsigned short* __restrict__ xb,
                                                  const unsigned short* __restrict__ wb,
                                                  unsigned short* __restrict__ aw,
                                                  unsigned short* __restrict__ bw) {
  __shared__ __align__(16) unsigned short lds[65536];   // 128 KiB

  const int tid = threadIdx.x;
  const int w = tid >> 6;          // wave 0..7
  const int lane = tid & 63;
  const int wm = w >> 2;           // 0..1 : M-half
  const int wn = w & 3;            // 0..3 : N-quarter (0,1 hidden / 2,3 gate)
  const int fr = lane & 15;
  const int kg = lane >> 4;        // 0..3

  // T1 bijective XCD swizzle: 1024 blocks = 256 mblk x 4 nblk
  const int orig = blockIdx.x;
  const int wg = (orig & 7) * 128 + (orig >> 3);
  const int mblk = wg >> 2;
  const int nblk = wg & 3;
  const int m0 = mblk * 256;
  const int n0 = nblk * 128;       // channel base (128 channels per block)

  // staging lane coords (dest linear: wave-uniform base + lane*16B)
  const int srow = lane >> 3;                       // 0..7
  const int scol = (((lane & 7) ^ srow) << 3);      // pre-swizzled source col (elems)

  // stage one K-tile (A: 4 loads, B: 4 loads per thread) into bank
  auto stage_kt = [&](int bank, int kt) {
    const int k0 = kt << 6;
#pragma unroll
    for (int hh = 0; hh < 4; ++hh) {               // 4 x 64-row rounds cover 256 rows
      int rowb = hh * 64 + (w << 3);               // wave-uniform
      int row = rowb + srow;
      const unsigned short* srcA = xb + (size_t)(m0 + row) * NK + k0 + scol;
      __builtin_amdgcn_global_load_lds(
          (const __attribute__((address_space(1))) void*)srcA,
          (__attribute__((address_space(3))) void*)(lds + bank * 16384 + rowb * 64),
          16, 0, 0);
    }
#pragma unroll
    for (int hh = 0; hh < 4; ++hh) {
      int rowb = hh * 64 + (w << 3);
      int row = rowb + srow;
      int e = (row < 128) ? (n0 + row) : (384 + n0 + row);   // hidden | gate W-rows
      const unsigned short* srcB = wb + (size_t)e * NK + k0 + scol;
      __builtin_amdgcn_global_load_lds(
          (const __attribute__((address_space(1))) void*)srcB,
          (__attribute__((address_space(3))) void*)(lds + 32768 + bank * 16384 + rowb * 64),
          16, 0, 0);
    }
  };

  f32x4 acc[8][4];
#pragma unroll
  for (int i = 0; i < 8; ++i)
#pragma unroll
    for (int j = 0; j < 4; ++j) acc[i][j] = (f32x4)0.0f;

  bf16x8 af[4], bfr[4];
  const char* ldsc = (const char*)lds;

#define READ_A4(BANK, MI0, KK)                                                        \
  {                                                                                   \
    _Pragma("unroll")                                                                 \
    for (int m = 0; m < 4; ++m) {                                                     \
      int row = (wm << 7) + (((MI0) + m) << 4) + fr;                                  \
      int bo = (BANK) * 32768 + row * 128 + ((((KK) + (kg << 3)) << 1) ^ ((row & 7) << 4)); \
      af[m] = *reinterpret_cast<const bf16x8*>(ldsc + bo);                            \
    }                                                                                 \
  }

#define READ_B4(BANK, KK)                                                             \
  {                                                                                   \
    _Pragma("unroll")                                                                 \
    for (int n = 0; n < 4; ++n) {                                                     \
      int row = (wn << 6) + (n << 4) + fr;                                            \
      int bo = 65536 + (BANK) * 32768 + row * 128 + ((((KK) + (kg << 3)) << 1) ^ ((row & 7) << 4)); \
      bfr[n] = *reinterpret_cast<const bf16x8*>(ldsc + bo);                           \
    }                                                                                 \
  }

#define MFMA16(MI0)                                                                   \
  {                                                                                   \
    _Pragma("unroll")                                                                 \
    for (int m = 0; m < 4; ++m)                                                       \
      _Pragma("unroll")                                                               \
      for (int n = 0; n < 4; ++n)                                                     \
        acc[(MI0) + m][n] = __builtin_amdgcn_mfma_f32_16x16x32_bf16(af[m], bfr[n],    \
                                                   acc[(MI0) + m][n], 0, 0, 0);       \
  }

// phase: ds_reads + optional stage -> barrier -> lgkm(0) -> MFMA quadrant
#define PH(BANK, MI0, KK, RB, ...)                                                    \
  {                                                                                   \
    READ_A4(BANK, MI0, KK);                                                           \
    if (RB) READ_B4(BANK, KK);                                                        \
    __VA_ARGS__;                                                                      \
    __builtin_amdgcn_s_barrier();                                                     \
    asm volatile("s_waitcnt lgkmcnt(0)" ::: "memory");                                \
    __builtin_amdgcn_sched_barrier(0);                                                \
    __builtin_amdgcn_s_setprio(1);                                                    \
    MFMA16(MI0);                                                                      \
    __builtin_amdgcn_s_setprio(0);                                                    \
  }

#define BAR() __builtin_amdgcn_s_barrier()
#define VM0() asm volatile("s_waitcnt vmcnt(0)" ::: "memory")

  // prologue: stage kt0 -> bank0
  stage_kt(0, 0);
  VM0();
  BAR();

#pragma unroll 1
  for (int i = 0; i < 4; ++i) {
    const int kt1 = 2 * i + 1;
    const int kt2 = 2 * i + 2;
    // phases 1-4: compute kt=2i from bank0; phase 1 stages kt1 -> bank1
    PH(0, 0, 0, 1, stage_kt(1, kt1));
    BAR();
    PH(0, 4, 0, 0, );
    BAR();
    PH(0, 0, 32, 1, );
    BAR();
    PH(0, 4, 32, 0, );
    VM0();          // kt1's 8 loads are the only outstanding -> bank1 complete
    BAR();
    // phases 5-8: compute kt1 from bank1; phase 5 stages kt2 -> bank0
    PH(1, 0, 0, 1, if (i < 3) stage_kt(0, kt2));
    BAR();
    PH(1, 4, 0, 0, );
    BAR();
    PH(1, 0, 32, 1, );
    BAR();
    PH(1, 4, 32, 0, );
    VM0();          // kt2's loads complete -> bank0 ready for next iteration
    BAR();
  }

  // ---------------- epilogue ----------------
  // gate waves (wn>=2) publish f32 gate values via LDS (kg-XOR swizzled),
  // hidden waves (wn<2) fuse a=sigmoid(-gate), b=sigmoid(gate)*g(hidden).
  float* gbuf = reinterpret_cast<float*>(lds);   // 256 x 128 f32 = 128KB
  if (wn >= 2) {
    const int cb = (wn - 2) << 6;
#pragma unroll
    for (int mi = 0; mi < 8; ++mi)
#pragma unroll
      for (int ni = 0; ni < 4; ++ni)
#pragma unroll
        for (int r = 0; r < 4; ++r) {
          int row = (wm << 7) + (mi << 4) + (kg << 2) + r;
          int ch = cb + (ni << 4) + fr;
          gbuf[(row << 7) + (ch ^ (((row >> 2) & 3) << 4))] = acc[mi][ni][r];
        }
  }
  asm volatile("s_waitcnt lgkmcnt(0)" ::: "memory");
  __builtin_amdgcn_s_barrier();
  if (wn < 2) {
    const int cb = wn << 6;
#pragma unroll
    for (int mi = 0; mi < 8; ++mi)
#pragma unroll
      for (int ni = 0; ni < 4; ++ni)
#pragma unroll
        for (int r = 0; r < 4; ++r) {
          int row = (wm << 7) + (mi << 4) + (kg << 2) + r;
          int ch = cb + (ni << 4) + fr;
          float hid = acc[mi][ni][r];
          float gat = gbuf[(row << 7) + (ch ^ (((row >> 2) & 3) << 4))];
          float a = 1.0f / (1.0f + __expf(gat));     // sigmoid(-gate)
          float z = 1.0f - a;                        // sigmoid(gate)
          float g = (hid >= 0.0f) ? (hid + 0.5f) : (1.0f / (1.0f + __expf(-hid)));
          float bb = z * g;
          size_t o = (size_t)(m0 + row) * ND + n0 + ch;
          aw[o] = f2bf(a);
          bw[o] = f2bf(bb);
        }
  }
#undef PH
#undef BAR
#undef VM0
#undef READ_A4
#undef READ_B4
#undef MFMA16
}

// ---------------- scan pass1: per-chunk (A,B) aggregates ----------------
// chunk L=128, 64 chunks/seq; 2 channels per thread (uint = 2 bf16)
__global__ __launch_bounds__(256) void scan_pass1(const unsigned short* __restrict__ aw,
                                                  const unsigned short* __restrict__ bw,
                                                  float* __restrict__ aggA,
                                                  float* __restrict__ aggB) {
  int bid = blockIdx.x;        // 8*64
  int b = bid >> 6;
  int c = bid & 63;
  int d2 = threadIdx.x;        // channel-pair 0..255
  const uint32_t* ap = reinterpret_cast<const uint32_t*>(aw);
  const uint32_t* bp = reinterpret_cast<const uint32_t*>(bw);
  size_t base = (size_t)(b * NS + c * 128) * 256 + d2;
  float A0 = 1.0f, A1 = 1.0f, B0 = 0.0f, B1 = 0.0f;
#pragma unroll 8
  for (int t = 0; t < 128; ++t) {
    uint32_t ua = ap[base + (size_t)t * 256];
    uint32_t ub = bp[base + (size_t)t * 256];
    float a0 = __uint_as_float(ua << 16);
    float a1 = __uint_as_float(ua & 0xffff0000u);
    float v0 = __uint_as_float(ub << 16);
    float v1 = __uint_as_float(ub & 0xffff0000u);
    B0 = fmaf(a0, B0, v0); A0 *= a0;
    B1 = fmaf(a1, B1, v1); A1 *= a1;
  }
  int o = (b * 64 + c) * ND + d2 * 2;
  *reinterpret_cast<float2*>(&aggA[o]) = make_float2(A0, A1);
  *reinterpret_cast<float2*>(&aggB[o]) = make_float2(B0, B1);
}

// ---------------- scan pass2: prefix + rescan, write out f32 ----------------
__global__ __launch_bounds__(256) void scan_pass2(const unsigned short* __restrict__ aw,
                                                  const unsigned short* __restrict__ bw,
                                                  const float* __restrict__ aggA,
                                                  const float* __restrict__ aggB,
                                                  float* __restrict__ out,
                                                  float* __restrict__ nextp) {
  int bid = blockIdx.x;
  int b = bid >> 6;
  int c = bid & 63;
  int d2 = threadIdx.x;

  float h0 = 0.0f, h1 = 0.0f;
  for (int cc = 0; cc < c; ++cc) {
    int o = (b * 64 + cc) * ND + d2 * 2;
    float2 Aa = *reinterpret_cast<const float2*>(&aggA[o]);
    float2 Bb = *reinterpret_cast<const float2*>(&aggB[o]);
    h0 = fmaf(Aa.x, h0, Bb.x);
    h1 = fmaf(Aa.y, h1, Bb.y);
  }
  const uint32_t* ap = reinterpret_cast<const uint32_t*>(aw);
  const uint32_t* bp = reinterpret_cast<const uint32_t*>(bw);
  size_t base = (size_t)(b * NS + c * 128) * 256 + d2;
#pragma unroll 4
  for (int t = 0; t < 128; ++t) {
    uint32_t ua = ap[base + (size_t)t * 256];
    uint32_t ub = bp[base + (size_t)t * 256];
    float a0 = __uint_as_float(ua << 16);
    float a1 = __uint_as_float(ua & 0xffff0000u);
    float v0 = __uint_as_float(ub << 16);
    float v1 = __uint_as_float(ub & 0xffff0000u);
    h0 = fmaf(a0, h0, v0);
    h1 = fmaf(a1, h1, v1);
    *reinterpret_cast<float2*>(&out[(base + (size_t)t * 256) * 2]) = make_float2(h0, h1);
  }
  if (c == 63) {
    *reinterpret_cast<float2*>(&nextp[b * ND + d2 * 2]) = make_float2(h0, h1);
  }
}

// ---------------- launcher ----------------
extern "C" void kernel_launch(void* const* d_in, const int* in_sizes, int n_in,
                              void* d_out, int out_size, void* d_ws, size_t ws_size,
                              hipStream_t stream) {
  const float* x = (const float*)d_in[0];   // (8, 8192, 512) f32
  const float* W = (const float*)d_in[1];   // (1024, 512) f32
  float* out = (float*)d_out;               // 33554432 + 4096 f32

  char* ws = (char*)d_ws;
  unsigned short* xb  = (unsigned short*)ws;                              // 64 MB
  unsigned short* wbf = (unsigned short*)(ws + (size_t)64 * 1024 * 1024); // 1 MB
  unsigned short* aw  = (unsigned short*)(ws + (size_t)65 * 1024 * 1024); // 64 MB
  unsigned short* bw  = (unsigned short*)(ws + (size_t)129 * 1024 * 1024);// 64 MB
  float* aggA = (float*)(ws + (size_t)193 * 1024 * 1024);                 // 1 MB
  float* aggB = (float*)(ws + (size_t)194 * 1024 * 1024);                 // 1 MB
  float* nextp = out + (size_t)NM * ND;

  cvt_bf16<<<16384, 256, 0, stream>>>(x, xb, (NM * NK) / 8);
  cvt_bf16<<<256, 256, 0, stream>>>(W, wbf, (1024 * NK) / 8);
  gemm_ab<<<1024, 512, 0, stream>>>(xb, wbf, aw, bw);
  scan_pass1<<<512, 256, 0, stream>>>(aw, bw, aggA, aggB);
  scan_pass2<<<512, 256, 0, stream>>>(aw, bw, aggA, aggB, out, nextp);
}

// Round 6
// 271.629 us; speedup vs baseline: 1.3013x; 1.3013x over previous
//
#include <hip/hip_runtime.h>
#include <hip/hip_bf16.h>
#include <stdint.h>

typedef float f32x4 __attribute__((ext_vector_type(4)));
typedef __bf16 bf16x8 __attribute__((ext_vector_type(8)));
typedef unsigned short ushort8 __attribute__((ext_vector_type(8)));

#define NB 8
#define NS 8192
#define ND 512
#define NM (NB * NS)      // 65536 rows
#define NK 512            // reduction dim

// ---------------- f32 -> bf16 (RNE) ----------------
__device__ __forceinline__ unsigned short f2bf(float f) {
  unsigned u = __float_as_uint(f);
  u += 0x7FFFu + ((u >> 16) & 1u);
  return (unsigned short)(u >> 16);
}

__global__ __launch_bounds__(256) void cvt_bf16(const float* __restrict__ src,
                                                unsigned short* __restrict__ dst,
                                                int n8) {
  int i = blockIdx.x * 256 + threadIdx.x;
  if (i >= n8) return;
  const float4* s = reinterpret_cast<const float4*>(src + (size_t)i * 8);
  float4 v0 = s[0], v1 = s[1];
  ushort8 o;
  o[0] = f2bf(v0.x); o[1] = f2bf(v0.y); o[2] = f2bf(v0.z); o[3] = f2bf(v0.w);
  o[4] = f2bf(v1.x); o[5] = f2bf(v1.y); o[6] = f2bf(v1.z); o[7] = f2bf(v1.w);
  *reinterpret_cast<ushort8*>(dst + (size_t)i * 8) = o;
}

// ---------------- bf16 GEMM + a/b epilogue (minimum 2-phase, T3 recipe) ----------------
// Block: 128 rows x (64 hidden cols + matching 64 gate cols). 4 waves, BK=64.
// Double-buffered LDS (2 x 32KB). Per K-tile: issue next-tile global_load_lds
// FIRST, then ds_read+MFMA current buffer, then ONE __syncthreads() (its
// vmcnt(0) drain lands after the whole compute phase). T2 XOR-swizzle via
// pre-swizzled global source; T1 bijective XCD grid swizzle. a,b stored bf16.
__global__ __launch_bounds__(256) void gemm_ab(const unsigned short* __restrict__ xb,
                                               const unsigned short* __restrict__ wb,
                                               unsigned short* __restrict__ aw,
                                               unsigned short* __restrict__ bw) {
  __shared__ __align__(16) unsigned short lds[2 * 2 * 128 * 64]; // buf{0,1} x (A 16KB | B 16KB)
  float* gbuf = reinterpret_cast<float*>(lds);                   // 32KB alias (epilogue)

  const int tid = threadIdx.x;
  const int w = tid >> 6;
  const int lane = tid & 63;
  const int wr = w >> 1;          // row-half
  const int wc = w & 1;           // 0: hidden cols, 1: gate cols
  // T1 bijective XCD swizzle: 4096 = 512 mblk x 8 nblk
  const int orig = blockIdx.x;
  const int wg = (orig & 7) * 512 + (orig >> 3);
  const int mblk = wg >> 3;
  const int nblk = wg & 7;
  const int m0 = mblk * 128;
  const int n0 = nblk * 64;

  const int lrow = lane >> 3;                    // 0..7
  const int lcol = (((lane & 7) ^ lrow) * 8);    // pre-swizzled source column (bf16)

  // stage one K-tile into buffer `buf` (A 16KB + B 16KB), dest linear
  auto stage = [&](int buf, int kt) {
    const int k0 = kt << 6;
    unsigned short* base = lds + buf * 16384;
#pragma unroll
    for (int i = 0; i < 4; ++i) {
      int row = i * 32 + w * 8 + lrow;
      const unsigned short* srcA = xb + (size_t)(m0 + row) * NK + k0 + lcol;
      __builtin_amdgcn_global_load_lds(
          (const __attribute__((address_space(1))) void*)srcA,
          (__attribute__((address_space(3))) void*)(base + i * 2048 + w * 512),
          16, 0, 0);
      int e = (row < 64) ? (n0 + row) : (448 + n0 + row);
      const unsigned short* srcB = wb + (size_t)e * NK + k0 + lcol;
      __builtin_amdgcn_global_load_lds(
          (const __attribute__((address_space(1))) void*)srcB,
          (__attribute__((address_space(3))) void*)(base + 8192 + i * 2048 + w * 512),
          16, 0, 0);
    }
  };

  f32x4 acc[4][4];
#pragma unroll
  for (int i = 0; i < 4; ++i)
#pragma unroll
    for (int j = 0; j < 4; ++j) acc[i][j] = (f32x4)0.0f;

  const int fr = lane & 15;
  const int kg = lane >> 4;

  // prologue: stage kt0 -> buf0 (syncthreads drains vmcnt+lgkm then barriers)
  stage(0, 0);
  __syncthreads();

#pragma unroll 1
  for (int kt = 0; kt < 8; ++kt) {
    const int cur = kt & 1;
    if (kt < 7) stage(cur ^ 1, kt + 1);   // issue next-tile loads FIRST

    const char* ldsA = (const char*)(lds + cur * 16384);
    const char* ldsB = ldsA + 16384;
#pragma unroll
    for (int kk = 0; kk < 64; kk += 32) {
      bf16x8 af[4], bfr[4];
#pragma unroll
      for (int i = 0; i < 4; ++i) {
        int rowA = wr * 64 + i * 16 + fr;
        int swzA = (kk * 2 + kg * 16) ^ ((rowA & 7) << 4);
        af[i] = *reinterpret_cast<const bf16x8*>(ldsA + rowA * 128 + swzA);
        int rowB = wc * 64 + i * 16 + fr;
        int swzB = (kk * 2 + kg * 16) ^ ((rowB & 7) << 4);
        bfr[i] = *reinterpret_cast<const bf16x8*>(ldsB + rowB * 128 + swzB);
      }
#pragma unroll
      for (int i = 0; i < 4; ++i)
#pragma unroll
        for (int j = 0; j < 4; ++j)
          acc[i][j] = __builtin_amdgcn_mfma_f32_16x16x32_bf16(af[i], bfr[j], acc[i][j], 0, 0, 0);
    }
    __syncthreads();   // one barrier per K-tile: drains staged loads + orders buffers
  }

  // ---------------- epilogue ----------------
  // gate waves publish gate values to LDS (swizzled), hidden waves fuse a,b.
  if (wc == 1) {
#pragma unroll
    for (int i = 0; i < 4; ++i)
#pragma unroll
      for (int j = 0; j < 4; ++j)
#pragma unroll
        for (int r = 0; r < 4; ++r) {
          int row = wr * 64 + i * 16 + kg * 4 + r;
          int dl = j * 16 + fr;
          int dsw = dl ^ (((row >> 2) & 3) << 4);
          gbuf[row * 64 + dsw] = acc[i][j][r];
        }
  }
  __syncthreads();
  if (wc == 0) {
#pragma unroll
    for (int i = 0; i < 4; ++i)
#pragma unroll
      for (int j = 0; j < 4; ++j)
#pragma unroll
        for (int r = 0; r < 4; ++r) {
          int row = wr * 64 + i * 16 + kg * 4 + r;
          int dl = j * 16 + fr;
          int dsw = dl ^ (((row >> 2) & 3) << 4);
          float hid = acc[i][j][r];
          float gat = gbuf[row * 64 + dsw];
          float a = 1.0f / (1.0f + __expf(gat));     // sigmoid(-gate)
          float z = 1.0f - a;                        // sigmoid(gate)
          float g = (hid >= 0.0f) ? (hid + 0.5f) : (1.0f / (1.0f + __expf(-hid)));
          float bb = z * g;
          size_t o = (size_t)(m0 + row) * ND + n0 + dl;
          aw[o] = f2bf(a);
          bw[o] = f2bf(bb);
        }
  }
}

// ---------------- scan pass1: per-chunk (A,B) aggregates ----------------
// chunk L=128, 64 chunks/seq; 2 channels per thread (uint = 2 bf16)
__global__ __launch_bounds__(256) void scan_pass1(const unsigned short* __restrict__ aw,
                                                  const unsigned short* __restrict__ bw,
                                                  float* __restrict__ aggA,
                                                  float* __restrict__ aggB) {
  int bid = blockIdx.x;        // 8*64
  int b = bid >> 6;
  int c = bid & 63;
  int d2 = threadIdx.x;        // channel-pair 0..255
  const uint32_t* ap = reinterpret_cast<const uint32_t*>(aw);
  const uint32_t* bp = reinterpret_cast<const uint32_t*>(bw);
  size_t base = (size_t)(b * NS + c * 128) * 256 + d2;
  float A0 = 1.0f, A1 = 1.0f, B0 = 0.0f, B1 = 0.0f;
#pragma unroll 8
  for (int t = 0; t < 128; ++t) {
    uint32_t ua = ap[base + (size_t)t * 256];
    uint32_t ub = bp[base + (size_t)t * 256];
    float a0 = __uint_as_float(ua << 16);
    float a1 = __uint_as_float(ua & 0xffff0000u);
    float v0 = __uint_as_float(ub << 16);
    float v1 = __uint_as_float(ub & 0xffff0000u);
    B0 = fmaf(a0, B0, v0); A0 *= a0;
    B1 = fmaf(a1, B1, v1); A1 *= a1;
  }
  int o = (b * 64 + c) * ND + d2 * 2;
  *reinterpret_cast<float2*>(&aggA[o]) = make_float2(A0, A1);
  *reinterpret_cast<float2*>(&aggB[o]) = make_float2(B0, B1);
}

// ---------------- scan pass2: prefix + rescan, write out f32 ----------------
__global__ __launch_bounds__(256) void scan_pass2(const unsigned short* __restrict__ aw,
                                                  const unsigned short* __restrict__ bw,
                                                  const float* __restrict__ aggA,
                                                  const float* __restrict__ aggB,
                                                  float* __restrict__ out,
                                                  float* __restrict__ nextp) {
  int bid = blockIdx.x;
  int b = bid >> 6;
  int c = bid & 63;
  int d2 = threadIdx.x;

  float h0 = 0.0f, h1 = 0.0f;
  for (int cc = 0; cc < c; ++cc) {
    int o = (b * 64 + cc) * ND + d2 * 2;
    float2 Aa = *reinterpret_cast<const float2*>(&aggA[o]);
    float2 Bb = *reinterpret_cast<const float2*>(&aggB[o]);
    h0 = fmaf(Aa.x, h0, Bb.x);
    h1 = fmaf(Aa.y, h1, Bb.y);
  }
  const uint32_t* ap = reinterpret_cast<const uint32_t*>(aw);
  const uint32_t* bp = reinterpret_cast<const uint32_t*>(bw);
  size_t base = (size_t)(b * NS + c * 128) * 256 + d2;
#pragma unroll 4
  for (int t = 0; t < 128; ++t) {
    uint32_t ua = ap[base + (size_t)t * 256];
    uint32_t ub = bp[base + (size_t)t * 256];
    float a0 = __uint_as_float(ua << 16);
    float a1 = __uint_as_float(ua & 0xffff0000u);
    float v0 = __uint_as_float(ub << 16);
    float v1 = __uint_as_float(ub & 0xffff0000u);
    h0 = fmaf(a0, h0, v0);
    h1 = fmaf(a1, h1, v1);
    *reinterpret_cast<float2*>(&out[(base + (size_t)t * 256) * 2]) = make_float2(h0, h1);
  }
  if (c == 63) {
    *reinterpret_cast<float2*>(&nextp[b * ND + d2 * 2]) = make_float2(h0, h1);
  }
}

// ---------------- launcher ----------------
extern "C" void kernel_launch(void* const* d_in, const int* in_sizes, int n_in,
                              void* d_out, int out_size, void* d_ws, size_t ws_size,
                              hipStream_t stream) {
  const float* x = (const float*)d_in[0];   // (8, 8192, 512) f32
  const float* W = (const float*)d_in[1];   // (1024, 512) f32
  float* out = (float*)d_out;               // 33554432 + 4096 f32

  char* ws = (char*)d_ws;
  unsigned short* xb  = (unsigned short*)ws;                              // 64 MB
  unsigned short* wbf = (unsigned short*)(ws + (size_t)64 * 1024 * 1024); // 1 MB
  unsigned short* aw  = (unsigned short*)(ws + (size_t)65 * 1024 * 1024); // 64 MB
  unsigned short* bw  = (unsigned short*)(ws + (size_t)129 * 1024 * 1024);// 64 MB
  float* aggA = (float*)(ws + (size_t)193 * 1024 * 1024);                 // 1 MB
  float* aggB = (float*)(ws + (size_t)194 * 1024 * 1024);                 // 1 MB
  float* nextp = out + (size_t)NM * ND;

  cvt_bf16<<<16384, 256, 0, stream>>>(x, xb, (NM * NK) / 8);
  cvt_bf16<<<256, 256, 0, stream>>>(W, wbf, (1024 * NK) / 8);
  gemm_ab<<<4096, 256, 0, stream>>>(xb, wbf, aw, bw);
  scan_pass1<<<512, 256, 0, stream>>>(aw, bw, aggA, aggB);
  scan_pass2<<<512, 256, 0, stream>>>(aw, bw, aggA, aggB, out, nextp);
}